// Round 3
// baseline (319.942 us; speedup 1.0000x reference)
//
#include <hip/hip_runtime.h>
#include <hip/hip_bf16.h>

#define N_TOTAL 384
#define BS 128
#define PD 8
#define D_FEAT 131072
#define EPS 1e-6f
#define KC 512
#define NKCH (D_FEAT / KC)   // 256
#define N_TILES 6            // upper-triangular 128x128 tiles of the 3x3 grid

typedef __attribute__((ext_vector_type(4))) float f32x4;
typedef __attribute__((ext_vector_type(8))) __bf16 bf16x8;

__device__ __forceinline__ bf16x8 cvt8(const float* p) {
    const float4 lo = *(const float4*)(p);
    const float4 hi = *(const float4*)(p + 4);
    bf16x8 r;
    r[0] = (__bf16)lo.x; r[1] = (__bf16)lo.y; r[2] = (__bf16)lo.z; r[3] = (__bf16)lo.w;
    r[4] = (__bf16)hi.x; r[5] = (__bf16)hi.y; r[6] = (__bf16)hi.z; r[7] = (__bf16)hi.w;
    return r;
}

// Symmetric accessor: only upper-triangular 128-tiles of G are populated.
__device__ __forceinline__ float gsym(const float* __restrict__ G, int i, int j) {
    return ((i >> 7) <= (j >> 7)) ? G[(size_t)i * N_TOTAL + j]
                                  : G[(size_t)j * N_TOTAL + i];
}

// G[i][j] = sum_k bf16(X[i][k]) * bf16(X[j][k]), fp32 accumulate.
// grid = N_TILES (fast dim, for column-stripe L2/L3 sharing) * NKCH.
// block = 256 (4 waves, 2x2 of 64x64).
__global__ __launch_bounds__(256) void gram_kernel(const float* __restrict__ X,
                                                   float* __restrict__ G) {
    const int bx   = blockIdx.x;
    const int tile = bx % N_TILES;
    const int kc   = bx / N_TILES;
    // upper-tri tile list: (0,0)(0,1)(0,2)(1,1)(1,2)(2,2)
    const int ti = (tile < 3) ? 0 : (tile < 5 ? 128 : 256);
    const int tj = (tile == 0) ? 0
                 : (tile == 1 || tile == 3) ? 128
                 : 256;

    const int wave = threadIdx.x >> 6;
    const int lane = threadIdx.x & 63;
    const int wr   = (wave >> 1) * 64;
    const int wc   = (wave & 1) * 64;
    const int r16  = lane & 15;
    const int kg   = lane >> 4;

    const size_t kbase = (size_t)kc * KC + (size_t)kg * 8;
    const float* pa[4];
    const float* pb[4];
#pragma unroll
    for (int m = 0; m < 4; m++) {
        pa[m] = X + (size_t)(ti + wr + m * 16 + r16) * D_FEAT + kbase;
        pb[m] = X + (size_t)(tj + wc + m * 16 + r16) * D_FEAT + kbase;
    }

    f32x4 acc[4][4];
#pragma unroll
    for (int m = 0; m < 4; m++)
#pragma unroll
        for (int n = 0; n < 4; n++) acc[m][n] = (f32x4)(0.0f);

    for (int kk = 0; kk < KC; kk += 32) {
        bf16x8 a[4], b[4];
#pragma unroll
        for (int m = 0; m < 4; m++) { a[m] = cvt8(pa[m]); pa[m] += 32; }
#pragma unroll
        for (int m = 0; m < 4; m++) { b[m] = cvt8(pb[m]); pb[m] += 32; }
#pragma unroll
        for (int m = 0; m < 4; m++)
#pragma unroll
            for (int n = 0; n < 4; n++)
                acc[m][n] = __builtin_amdgcn_mfma_f32_16x16x32_bf16(a[m], b[n], acc[m][n], 0, 0, 0);
    }

    // C/D layout (verified on gfx950): col = lane&15, row = (lane>>4)*4 + r
    const int crow = (lane >> 4) * 4;
    const int ccol = lane & 15;
#pragma unroll
    for (int m = 0; m < 4; m++)
#pragma unroll
        for (int n = 0; n < 4; n++)
#pragma unroll
            for (int r = 0; r < 4; r++)
                atomicAdd(&G[(size_t)(ti + wr + m * 16 + crow + r) * N_TOTAL +
                             (tj + wc + n * 16 + ccol)],
                          acc[m][n][r]);
}

// den[i] = sum over j with j%8 != i%8 of exp(10 * cos(i,j)).
// Norms taken from Gram diagonal (consistent with bf16 numerator).
__global__ __launch_bounds__(128) void den_kernel(const float* __restrict__ G,
                                                  float* __restrict__ den) {
    const int i = blockIdx.x;
    __shared__ float sInv[N_TOTAL];
    for (int j = threadIdx.x; j < N_TOTAL; j += 128) {
        const float n = sqrtf(G[(size_t)j * N_TOTAL + j]);
        sInv[j] = 1.0f / fmaxf(n, EPS);
    }
    __syncthreads();

    const float mi  = sInv[i] * 10.0f;   // 1/temp = 10
    const int   myc = i & 7;
    float s = 0.0f;
    for (int j = threadIdx.x; j < N_TOTAL; j += 128) {
        if ((j & 7) != myc)
            s += expf(gsym(G, i, j) * mi * sInv[j]);
    }
#pragma unroll
    for (int off = 32; off > 0; off >>= 1) s += __shfl_down(s, off, 64);
    __shared__ float partial[2];
    if ((threadIdx.x & 63) == 0) partial[threadIdx.x >> 6] = s;
    __syncthreads();
    if (threadIdx.x == 0) den[i] = partial[0] + partial[1];
}

__global__ __launch_bounds__(256) void loss_kernel(const float* __restrict__ G,
                                                   const float* __restrict__ den,
                                                   float* __restrict__ out) {
    __shared__ float sInv[N_TOTAL];
    for (int j = threadIdx.x; j < N_TOTAL; j += 256) {
        const float n = sqrtf(G[(size_t)j * N_TOTAL + j]);
        sInv[j] = 1.0f / fmaxf(n, EPS);
    }
    __syncthreads();

    float s = 0.0f;
    for (int idx = threadIdx.x; idx < 7 * BS; idx += 256) {
        const int p   = idx & (BS - 1);
        const int set = idx >> 7;
        int a, b;
        switch (set) {
            case 0:  a = p;                        b = BS + p;                      break;
            case 1:  a = (p + PD) % N_TOTAL;       b = (BS + p + PD) % N_TOTAL;     break;
            case 2:  a = p;                        b = (p + PD) % N_TOTAL;          break;
            case 3:  a = BS + p;                   b = (BS + p + PD) % N_TOTAL;     break;
            case 4:  a = 2 * BS + p;               b = (2 * BS + p + PD) % N_TOTAL; break;
            case 5:  a = BS + p;                   b = 2 * BS + p;                  break;
            default: a = (BS + p + PD) % N_TOTAL;  b = (2 * BS + p + PD) % N_TOTAL; break;
        }
        const float en = expf(gsym(G, a, b) * sInv[a] * sInv[b] * 10.0f);
        s += log1pf(den[a] / en) + log1pf(den[b] / en);
    }
#pragma unroll
    for (int off = 32; off > 0; off >>= 1) s += __shfl_down(s, off, 64);
    __shared__ float partial[4];
    if ((threadIdx.x & 63) == 0) partial[threadIdx.x >> 6] = s;
    __syncthreads();
    if (threadIdx.x == 0)
        out[0] = (partial[0] + partial[1] + partial[2] + partial[3]) / 768.0f;
}

extern "C" void kernel_launch(void* const* d_in, const int* in_sizes, int n_in,
                              void* d_out, int out_size, void* d_ws, size_t ws_size,
                              hipStream_t stream) {
    (void)in_sizes; (void)n_in; (void)out_size; (void)ws_size;
    const float* X   = (const float*)d_in[0];
    float*       out = (float*)d_out;
    float*       G   = (float*)d_ws;                       // 384*384 fp32
    float*       den = G + (size_t)N_TOTAL * N_TOTAL;      // 384 fp32

    hipMemsetAsync(G, 0, (size_t)N_TOTAL * N_TOTAL * sizeof(float), stream);
    gram_kernel<<<N_TILES * NKCH, 256, 0, stream>>>(X, G);
    den_kernel<<<N_TOTAL, 128, 0, stream>>>(G, den);
    loss_kernel<<<1, 256, 0, stream>>>(G, den, out);
}

// Round 4
// 187.479 us; speedup vs baseline: 1.7065x; 1.7065x over previous
//
#include <hip/hip_runtime.h>
#include <hip/hip_bf16.h>

#define N_TOTAL 384
#define BS 128
#define PD 8
#define D_FEAT 131072
#define EPS 1e-6f
#define N_TILES 6            // upper-triangular 128x128 tiles of the 3x3 grid

// bf16-path split-K
#define KC2 1024
#define NKCH2 (D_FEAT / KC2)   // 128
// fp32 fallback split-K
#define KC 512
#define NKCH (D_FEAT / KC)     // 256

typedef __attribute__((ext_vector_type(4))) float f32x4;
typedef __attribute__((ext_vector_type(8))) __bf16 bf16x8;

__device__ __forceinline__ bf16x8 cvt8(const float* p) {
    const float4 lo = *(const float4*)(p);
    const float4 hi = *(const float4*)(p + 4);
    bf16x8 r;
    r[0] = (__bf16)lo.x; r[1] = (__bf16)lo.y; r[2] = (__bf16)lo.z; r[3] = (__bf16)lo.w;
    r[4] = (__bf16)hi.x; r[5] = (__bf16)hi.y; r[6] = (__bf16)hi.z; r[7] = (__bf16)hi.w;
    return r;
}

// Symmetric accessor: only upper-triangular 128-tiles of G are populated.
__device__ __forceinline__ float gsym(const float* __restrict__ G, int i, int j) {
    return ((i >> 7) <= (j >> 7)) ? G[(size_t)i * N_TOTAL + j]
                                  : G[(size_t)j * N_TOTAL + i];
}

// ---------------- pass 1: fp32 -> bf16 streaming convert ----------------
__global__ __launch_bounds__(256) void cvt_kernel(const float* __restrict__ X,
                                                  __bf16* __restrict__ Xb) {
    const size_t nUnits = (size_t)N_TOTAL * D_FEAT / 8;   // 8 elems per unit
    const size_t stride = (size_t)gridDim.x * blockDim.x;
    for (size_t u = (size_t)blockIdx.x * blockDim.x + threadIdx.x; u < nUnits; u += stride) {
        *(bf16x8*)(Xb + u * 8) = cvt8(X + u * 8);
    }
}

// ---------------- pass 2: Gram from bf16, register double-buffered ----------------
#define LOADAB(ar, br, off)                                           \
    _Pragma("unroll") for (int m = 0; m < 4; m++) {                   \
        ar[m] = *(const bf16x8*)(pa[m] + (off));                      \
        br[m] = *(const bf16x8*)(pb[m] + (off));                      \
    }

#define MFMAAB(ar, br)                                                \
    _Pragma("unroll") for (int m = 0; m < 4; m++)                     \
    _Pragma("unroll") for (int n = 0; n < 4; n++)                     \
        acc[m][n] = __builtin_amdgcn_mfma_f32_16x16x32_bf16(ar[m], br[n], acc[m][n], 0, 0, 0);

__global__ __launch_bounds__(256) void gram_bf16_kernel(const __bf16* __restrict__ Xb,
                                                        float* __restrict__ G) {
    const int bx   = blockIdx.x;
    const int tile = bx % N_TILES;
    const int kc   = bx / N_TILES;
    // upper-tri tile list: (0,0)(0,1)(0,2)(1,1)(1,2)(2,2)
    const int ti = (tile < 3) ? 0 : (tile < 5 ? 128 : 256);
    const int tj = (tile == 0) ? 0
                 : (tile == 1 || tile == 3) ? 128
                 : 256;

    const int wave = threadIdx.x >> 6;
    const int lane = threadIdx.x & 63;
    const int wr   = (wave >> 1) * 64;
    const int wc   = (wave & 1) * 64;
    const int r16  = lane & 15;
    const int kg   = lane >> 4;

    const size_t kbase = (size_t)kc * KC2 + (size_t)kg * 8;
    const __bf16* pa[4];
    const __bf16* pb[4];
#pragma unroll
    for (int m = 0; m < 4; m++) {
        pa[m] = Xb + (size_t)(ti + wr + m * 16 + r16) * D_FEAT + kbase;
        pb[m] = Xb + (size_t)(tj + wc + m * 16 + r16) * D_FEAT + kbase;
    }

    f32x4 acc[4][4];
#pragma unroll
    for (int m = 0; m < 4; m++)
#pragma unroll
        for (int n = 0; n < 4; n++) acc[m][n] = (f32x4)(0.0f);

    bf16x8 a0[4], b0[4], a1[4], b1[4];
    LOADAB(a0, b0, 0)
    for (int kk = 0; kk < KC2 - 64; kk += 64) {
        LOADAB(a1, b1, kk + 32)     // in flight during the next MFMA batch
        MFMAAB(a0, b0)
        LOADAB(a0, b0, kk + 64)
        MFMAAB(a1, b1)
    }
    LOADAB(a1, b1, KC2 - 32)
    MFMAAB(a0, b0)
    MFMAAB(a1, b1)

    // C/D layout (verified on gfx950): col = lane&15, row = (lane>>4)*4 + r
    const int crow = (lane >> 4) * 4;
    const int ccol = lane & 15;
#pragma unroll
    for (int m = 0; m < 4; m++)
#pragma unroll
        for (int n = 0; n < 4; n++)
#pragma unroll
            for (int r = 0; r < 4; r++)
                atomicAdd(&G[(size_t)(ti + wr + m * 16 + crow + r) * N_TOTAL +
                             (tj + wc + n * 16 + ccol)],
                          acc[m][n][r]);
}

// ---------------- fp32 fallback (round-3 path, used if ws too small) ----------------
__global__ __launch_bounds__(256) void gram_kernel(const float* __restrict__ X,
                                                   float* __restrict__ G) {
    const int bx   = blockIdx.x;
    const int tile = bx % N_TILES;
    const int kc   = bx / N_TILES;
    const int ti = (tile < 3) ? 0 : (tile < 5 ? 128 : 256);
    const int tj = (tile == 0) ? 0
                 : (tile == 1 || tile == 3) ? 128
                 : 256;

    const int wave = threadIdx.x >> 6;
    const int lane = threadIdx.x & 63;
    const int wr   = (wave >> 1) * 64;
    const int wc   = (wave & 1) * 64;
    const int r16  = lane & 15;
    const int kg   = lane >> 4;

    const size_t kbase = (size_t)kc * KC + (size_t)kg * 8;
    const float* pa[4];
    const float* pb[4];
#pragma unroll
    for (int m = 0; m < 4; m++) {
        pa[m] = X + (size_t)(ti + wr + m * 16 + r16) * D_FEAT + kbase;
        pb[m] = X + (size_t)(tj + wc + m * 16 + r16) * D_FEAT + kbase;
    }

    f32x4 acc[4][4];
#pragma unroll
    for (int m = 0; m < 4; m++)
#pragma unroll
        for (int n = 0; n < 4; n++) acc[m][n] = (f32x4)(0.0f);

    for (int kk = 0; kk < KC; kk += 32) {
        bf16x8 a[4], b[4];
#pragma unroll
        for (int m = 0; m < 4; m++) { a[m] = cvt8(pa[m]); pa[m] += 32; }
#pragma unroll
        for (int m = 0; m < 4; m++) { b[m] = cvt8(pb[m]); pb[m] += 32; }
        MFMAAB(a, b)
    }

    const int crow = (lane >> 4) * 4;
    const int ccol = lane & 15;
#pragma unroll
    for (int m = 0; m < 4; m++)
#pragma unroll
        for (int n = 0; n < 4; n++)
#pragma unroll
            for (int r = 0; r < 4; r++)
                atomicAdd(&G[(size_t)(ti + wr + m * 16 + crow + r) * N_TOTAL +
                             (tj + wc + n * 16 + ccol)],
                          acc[m][n][r]);
}

// ---------------- pass 3/4: denominators and loss ----------------
__global__ __launch_bounds__(128) void den_kernel(const float* __restrict__ G,
                                                  float* __restrict__ den) {
    const int i = blockIdx.x;
    __shared__ float sInv[N_TOTAL];
    for (int j = threadIdx.x; j < N_TOTAL; j += 128) {
        const float n = sqrtf(G[(size_t)j * N_TOTAL + j]);
        sInv[j] = 1.0f / fmaxf(n, EPS);
    }
    __syncthreads();

    const float mi  = sInv[i] * 10.0f;   // 1/temp = 10
    const int   myc = i & 7;
    float s = 0.0f;
    for (int j = threadIdx.x; j < N_TOTAL; j += 128) {
        if ((j & 7) != myc)
            s += expf(gsym(G, i, j) * mi * sInv[j]);
    }
#pragma unroll
    for (int off = 32; off > 0; off >>= 1) s += __shfl_down(s, off, 64);
    __shared__ float partial[2];
    if ((threadIdx.x & 63) == 0) partial[threadIdx.x >> 6] = s;
    __syncthreads();
    if (threadIdx.x == 0) den[i] = partial[0] + partial[1];
}

__global__ __launch_bounds__(256) void loss_kernel(const float* __restrict__ G,
                                                   const float* __restrict__ den,
                                                   float* __restrict__ out) {
    __shared__ float sInv[N_TOTAL];
    for (int j = threadIdx.x; j < N_TOTAL; j += 256) {
        const float n = sqrtf(G[(size_t)j * N_TOTAL + j]);
        sInv[j] = 1.0f / fmaxf(n, EPS);
    }
    __syncthreads();

    float s = 0.0f;
    for (int idx = threadIdx.x; idx < 7 * BS; idx += 256) {
        const int p   = idx & (BS - 1);
        const int set = idx >> 7;
        int a, b;
        switch (set) {
            case 0:  a = p;                        b = BS + p;                      break;
            case 1:  a = (p + PD) % N_TOTAL;       b = (BS + p + PD) % N_TOTAL;     break;
            case 2:  a = p;                        b = (p + PD) % N_TOTAL;          break;
            case 3:  a = BS + p;                   b = (BS + p + PD) % N_TOTAL;     break;
            case 4:  a = 2 * BS + p;               b = (2 * BS + p + PD) % N_TOTAL; break;
            case 5:  a = BS + p;                   b = 2 * BS + p;                  break;
            default: a = (BS + p + PD) % N_TOTAL;  b = (2 * BS + p + PD) % N_TOTAL; break;
        }
        const float en = expf(gsym(G, a, b) * sInv[a] * sInv[b] * 10.0f);
        s += log1pf(den[a] / en) + log1pf(den[b] / en);
    }
#pragma unroll
    for (int off = 32; off > 0; off >>= 1) s += __shfl_down(s, off, 64);
    __shared__ float partial[4];
    if ((threadIdx.x & 63) == 0) partial[threadIdx.x >> 6] = s;
    __syncthreads();
    if (threadIdx.x == 0)
        out[0] = (partial[0] + partial[1] + partial[2] + partial[3]) / 768.0f;
}

extern "C" void kernel_launch(void* const* d_in, const int* in_sizes, int n_in,
                              void* d_out, int out_size, void* d_ws, size_t ws_size,
                              hipStream_t stream) {
    (void)in_sizes; (void)n_in; (void)out_size;
    const float* X   = (const float*)d_in[0];
    float*       out = (float*)d_out;
    float*       G   = (float*)d_ws;                       // 384*384 fp32
    float*       den = G + (size_t)N_TOTAL * N_TOTAL;      // 384 fp32

    hipMemsetAsync(G, 0, (size_t)N_TOTAL * N_TOTAL * sizeof(float), stream);

    const size_t xbOff  = 1u << 20;                        // 1 MB offset, 16B-aligned
    const size_t need   = xbOff + sizeof(__bf16) * (size_t)N_TOTAL * D_FEAT;
    if (ws_size >= need) {
        __bf16* Xb = (__bf16*)((char*)d_ws + xbOff);
        cvt_kernel<<<2048, 256, 0, stream>>>(X, Xb);
        gram_bf16_kernel<<<N_TILES * NKCH2, 256, 0, stream>>>(Xb, G);
    } else {
        gram_kernel<<<N_TILES * NKCH, 256, 0, stream>>>(X, G);
    }
    den_kernel<<<N_TOTAL, 128, 0, stream>>>(G, den);
    loss_kernel<<<1, 256, 0, stream>>>(G, den, out);
}

// Round 5
// 144.865 us; speedup vs baseline: 2.2085x; 1.2942x over previous
//
#include <hip/hip_runtime.h>
#include <hip/hip_bf16.h>

#define N_TOTAL 384
#define BS 128
#define PD 8
#define D_FEAT 131072
#define EPS 1e-6f
#define N_TILES 6            // upper-triangular 128x128 tiles of the 3x3 grid

// bf16 LDS-staged gram
#define KC2 1024
#define NKCH2 (D_FEAT / KC2)   // 128
#define BK 64
#define NIT (KC2 / BK)         // 16
// fp32 fallback split-K
#define KC 512
#define NKCH (D_FEAT / KC)     // 256

typedef __attribute__((ext_vector_type(4))) float f32x4;
typedef __attribute__((ext_vector_type(8))) __bf16 bf16x8;

typedef __attribute__((address_space(1))) const unsigned int gu32;
typedef __attribute__((address_space(3))) unsigned int lu32;

__device__ __forceinline__ void gload16(const void* g, void* l) {
    // async global->LDS DMA, 16B per lane; LDS dest = uniform base + lane*16
    __builtin_amdgcn_global_load_lds((gu32*)g, (lu32*)l, 16, 0, 0);
}

__device__ __forceinline__ bf16x8 cvt8(const float* p) {
    const float4 lo = *(const float4*)(p);
    const float4 hi = *(const float4*)(p + 4);
    bf16x8 r;
    r[0] = (__bf16)lo.x; r[1] = (__bf16)lo.y; r[2] = (__bf16)lo.z; r[3] = (__bf16)lo.w;
    r[4] = (__bf16)hi.x; r[5] = (__bf16)hi.y; r[6] = (__bf16)hi.z; r[7] = (__bf16)hi.w;
    return r;
}

// Symmetric accessor: only upper-triangular 128-tiles of G are populated.
__device__ __forceinline__ float gsym(const float* __restrict__ G, int i, int j) {
    return ((i >> 7) <= (j >> 7)) ? G[(size_t)i * N_TOTAL + j]
                                  : G[(size_t)j * N_TOTAL + i];
}

// ---------------- pass 1: fp32 -> bf16 streaming convert ----------------
__global__ __launch_bounds__(256) void cvt_kernel(const float* __restrict__ X,
                                                  __bf16* __restrict__ Xb) {
    const size_t nUnits = (size_t)N_TOTAL * D_FEAT / 8;   // 8 elems per unit
    const size_t stride = (size_t)gridDim.x * blockDim.x;
    for (size_t u = (size_t)blockIdx.x * blockDim.x + threadIdx.x; u < nUnits; u += stride) {
        *(bf16x8*)(Xb + u * 8) = cvt8(X + u * 8);
    }
}

// ---------------- pass 2: Gram from bf16, LDS 2-phase async pipeline ----------------
// LDS buffer layout: [128 rows][64 cols bf16] = row stride 128 B, XOR-swizzled:
// logical (row, colbyte c) lives at byte row*128 + (c ^ ((row&7)<<4)).
// global_load_lds writes linearly, so the SOURCE address carries the inverse
// (= same) permutation (rule: both-sides-or-neither).
#define MFMAAB(ar, br)                                                \
    _Pragma("unroll") for (int m = 0; m < 4; m++)                     \
    _Pragma("unroll") for (int n = 0; n < 4; n++)                     \
        acc[m][n] = __builtin_amdgcn_mfma_f32_16x16x32_bf16(ar[m], br[n], acc[m][n], 0, 0, 0);

__global__ __launch_bounds__(256) void gram_bf16_kernel(const __bf16* __restrict__ Xb,
                                                        float* __restrict__ G) {
    __shared__ __bf16 sA[2][128 * BK];
    __shared__ __bf16 sB[2][128 * BK];

    const int bx   = blockIdx.x;
    const int tile = bx % N_TILES;
    const int kc   = bx / N_TILES;
    // upper-tri tile list: (0,0)(0,1)(0,2)(1,1)(1,2)(2,2)
    const int ti = (tile < 3) ? 0 : (tile < 5 ? 128 : 256);
    const int tj = (tile == 0) ? 0
                 : (tile == 1 || tile == 3) ? 128
                 : 256;
    const bool diag = (ti == tj);

    const int wave = threadIdx.x >> 6;
    const int lane = threadIdx.x & 63;
    const int wr   = (wave >> 1) * 64;
    const int wc   = (wave & 1) * 64;
    const int r16  = lane & 15;
    const int kg   = lane >> 4;

    const size_t kbase = (size_t)kc * KC2;

    // ---- staging geometry (per wave: 32 rows of each panel, 4 instrs, 8 rows each)
    const int rloc0 = wave * 32 + (lane >> 3);          // + s*8 per instr
    const int csrc  = ((lane & 7) * 16) ^ ((rloc0 & 7) << 4);  // swizzled source col-byte

    const char* XbB = (const char*)Xb;

    // ---- compute-phase ds_read geometry
    const int xsw = (r16 & 7) << 4;                     // read-side XOR (row&7 == r16&7)

    f32x4 acc[4][4];
#pragma unroll
    for (int m = 0; m < 4; m++)
#pragma unroll
        for (int n = 0; n < 4; n++) acc[m][n] = (f32x4)(0.0f);

#define STAGE(buf, t)                                                                     \
    do {                                                                                  \
        const size_t kb = (kbase + (size_t)(t) * BK) * 2;                                 \
        _Pragma("unroll") for (int s = 0; s < 4; s++) {                                   \
            gload16(XbB + (size_t)(ti + rloc0 + s * 8) * (D_FEAT * 2) + kb + csrc,        \
                    (char*)sA[buf] + (wave * 32 + s * 8) * 128);                          \
        }                                                                                 \
        if (!diag) {                                                                      \
            _Pragma("unroll") for (int s = 0; s < 4; s++) {                               \
                gload16(XbB + (size_t)(tj + rloc0 + s * 8) * (D_FEAT * 2) + kb + csrc,    \
                        (char*)sB[buf] + (wave * 32 + s * 8) * 128);                      \
            }                                                                             \
        }                                                                                 \
    } while (0)

    STAGE(0, 0);
    __syncthreads();    // drains vmcnt(0): buf0 ready

    for (int t = 0; t < NIT; ++t) {
        const int b = t & 1;
        if (t + 1 < NIT) STAGE(b ^ 1, t + 1);          // in flight during compute below
        const char* bufA = (const char*)sA[b];
        const char* bufB = diag ? bufA : (const char*)sB[b];
#pragma unroll
        for (int ks = 0; ks < 2; ++ks) {
            const int coff = ((ks * 64 + kg * 16) ^ xsw);
            bf16x8 a[4], bb[4];
#pragma unroll
            for (int m = 0; m < 4; m++)
                a[m] = *(const bf16x8*)(bufA + (wr + m * 16 + r16) * 128 + coff);
#pragma unroll
            for (int n = 0; n < 4; n++)
                bb[n] = *(const bf16x8*)(bufB + (wc + n * 16 + r16) * 128 + coff);
            MFMAAB(a, bb)
        }
        __syncthreads();   // drains next-buffer stage + protects buffer reuse
    }
#undef STAGE

    // C/D layout (verified on gfx950): col = lane&15, row = (lane>>4)*4 + r
    const int crow = (lane >> 4) * 4;
    const int ccol = lane & 15;
#pragma unroll
    for (int m = 0; m < 4; m++)
#pragma unroll
        for (int n = 0; n < 4; n++)
#pragma unroll
            for (int r = 0; r < 4; r++)
                atomicAdd(&G[(size_t)(ti + wr + m * 16 + crow + r) * N_TOTAL +
                             (tj + wc + n * 16 + ccol)],
                          acc[m][n][r]);
}

// ---------------- fp32 fallback (round-3 path, used if ws too small) ----------------
__global__ __launch_bounds__(256) void gram_kernel(const float* __restrict__ X,
                                                   float* __restrict__ G) {
    const int bx   = blockIdx.x;
    const int tile = bx % N_TILES;
    const int kc   = bx / N_TILES;
    const int ti = (tile < 3) ? 0 : (tile < 5 ? 128 : 256);
    const int tj = (tile == 0) ? 0
                 : (tile == 1 || tile == 3) ? 128
                 : 256;

    const int wave = threadIdx.x >> 6;
    const int lane = threadIdx.x & 63;
    const int wr   = (wave >> 1) * 64;
    const int wc   = (wave & 1) * 64;
    const int r16  = lane & 15;
    const int kg   = lane >> 4;

    const size_t kbase = (size_t)kc * KC + (size_t)kg * 8;
    const float* pa[4];
    const float* pb[4];
#pragma unroll
    for (int m = 0; m < 4; m++) {
        pa[m] = X + (size_t)(ti + wr + m * 16 + r16) * D_FEAT + kbase;
        pb[m] = X + (size_t)(tj + wc + m * 16 + r16) * D_FEAT + kbase;
    }

    f32x4 acc[4][4];
#pragma unroll
    for (int m = 0; m < 4; m++)
#pragma unroll
        for (int n = 0; n < 4; n++) acc[m][n] = (f32x4)(0.0f);

    for (int kk = 0; kk < KC; kk += 32) {
        bf16x8 a[4], b[4];
#pragma unroll
        for (int m = 0; m < 4; m++) { a[m] = cvt8(pa[m]); pa[m] += 32; }
#pragma unroll
        for (int m = 0; m < 4; m++) { b[m] = cvt8(pb[m]); pb[m] += 32; }
        MFMAAB(a, b)
    }

    const int crow = (lane >> 4) * 4;
    const int ccol = lane & 15;
#pragma unroll
    for (int m = 0; m < 4; m++)
#pragma unroll
        for (int n = 0; n < 4; n++)
#pragma unroll
            for (int r = 0; r < 4; r++)
                atomicAdd(&G[(size_t)(ti + wr + m * 16 + crow + r) * N_TOTAL +
                             (tj + wc + n * 16 + ccol)],
                          acc[m][n][r]);
}

// ---------------- pass 3/4: denominators and loss ----------------
__global__ __launch_bounds__(128) void den_kernel(const float* __restrict__ G,
                                                  float* __restrict__ den) {
    const int i = blockIdx.x;
    __shared__ float sInv[N_TOTAL];
    for (int j = threadIdx.x; j < N_TOTAL; j += 128) {
        const float n = sqrtf(G[(size_t)j * N_TOTAL + j]);
        sInv[j] = 1.0f / fmaxf(n, EPS);
    }
    __syncthreads();

    const float mi  = sInv[i] * 10.0f;   // 1/temp = 10
    const int   myc = i & 7;
    float s = 0.0f;
    for (int j = threadIdx.x; j < N_TOTAL; j += 128) {
        if ((j & 7) != myc)
            s += expf(gsym(G, i, j) * mi * sInv[j]);
    }
#pragma unroll
    for (int off = 32; off > 0; off >>= 1) s += __shfl_down(s, off, 64);
    __shared__ float partial[2];
    if ((threadIdx.x & 63) == 0) partial[threadIdx.x >> 6] = s;
    __syncthreads();
    if (threadIdx.x == 0) den[i] = partial[0] + partial[1];
}

__global__ __launch_bounds__(256) void loss_kernel(const float* __restrict__ G,
                                                   const float* __restrict__ den,
                                                   float* __restrict__ out) {
    __shared__ float sInv[N_TOTAL];
    for (int j = threadIdx.x; j < N_TOTAL; j += 256) {
        const float n = sqrtf(G[(size_t)j * N_TOTAL + j]);
        sInv[j] = 1.0f / fmaxf(n, EPS);
    }
    __syncthreads();

    float s = 0.0f;
    for (int idx = threadIdx.x; idx < 7 * BS; idx += 256) {
        const int p   = idx & (BS - 1);
        const int set = idx >> 7;
        int a, b;
        switch (set) {
            case 0:  a = p;                        b = BS + p;                      break;
            case 1:  a = (p + PD) % N_TOTAL;       b = (BS + p + PD) % N_TOTAL;     break;
            case 2:  a = p;                        b = (p + PD) % N_TOTAL;          break;
            case 3:  a = BS + p;                   b = (BS + p + PD) % N_TOTAL;     break;
            case 4:  a = 2 * BS + p;               b = (2 * BS + p + PD) % N_TOTAL; break;
            case 5:  a = BS + p;                   b = 2 * BS + p;                  break;
            default: a = (BS + p + PD) % N_TOTAL;  b = (2 * BS + p + PD) % N_TOTAL; break;
        }
        const float en = expf(gsym(G, a, b) * sInv[a] * sInv[b] * 10.0f);
        s += log1pf(den[a] / en) + log1pf(den[b] / en);
    }
#pragma unroll
    for (int off = 32; off > 0; off >>= 1) s += __shfl_down(s, off, 64);
    __shared__ float partial[4];
    if ((threadIdx.x & 63) == 0) partial[threadIdx.x >> 6] = s;
    __syncthreads();
    if (threadIdx.x == 0)
        out[0] = (partial[0] + partial[1] + partial[2] + partial[3]) / 768.0f;
}

extern "C" void kernel_launch(void* const* d_in, const int* in_sizes, int n_in,
                              void* d_out, int out_size, void* d_ws, size_t ws_size,
                              hipStream_t stream) {
    (void)in_sizes; (void)n_in; (void)out_size;
    const float* X   = (const float*)d_in[0];
    float*       out = (float*)d_out;
    float*       G   = (float*)d_ws;                       // 384*384 fp32
    float*       den = G + (size_t)N_TOTAL * N_TOTAL;      // 384 fp32

    hipMemsetAsync(G, 0, (size_t)N_TOTAL * N_TOTAL * sizeof(float), stream);

    const size_t xbOff  = 1u << 20;                        // 1 MB offset, 16B-aligned
    const size_t need   = xbOff + sizeof(__bf16) * (size_t)N_TOTAL * D_FEAT;
    if (ws_size >= need) {
        __bf16* Xb = (__bf16*)((char*)d_ws + xbOff);
        cvt_kernel<<<2048, 256, 0, stream>>>(X, Xb);
        gram_bf16_kernel<<<N_TILES * NKCH2, 256, 0, stream>>>(Xb, G);
    } else {
        gram_kernel<<<N_TILES * NKCH, 256, 0, stream>>>(X, G);
    }
    den_kernel<<<N_TOTAL, 128, 0, stream>>>(G, den);
    loss_kernel<<<1, 256, 0, stream>>>(G, den, out);
}

// Round 6
// 111.722 us; speedup vs baseline: 2.8637x; 1.2967x over previous
//
#include <hip/hip_runtime.h>
#include <hip/hip_bf16.h>

#define N_TOTAL 384
#define BS 128
#define PD 8
#define D_FEAT 131072
#define EPS 1e-6f

#define NSTRIP 128
#define COLS_PER (D_FEAT / NSTRIP)   // 1024 cols per strip
#define CHUNK 32
#define NCH (COLS_PER / CHUNK)       // 32 chunks per strip
#define LROW 80                      // padded LDS row stride in bytes (64 data + 16 pad)

typedef __attribute__((ext_vector_type(4))) float f32x4;
typedef __attribute__((ext_vector_type(8))) __bf16 bf16x8;
typedef __attribute__((ext_vector_type(4))) __bf16 bf16x4;

// Per-wave output subtile tables (64-row/col band indices, 0..5).
// flavor 0 = diagonal 128-tiles (0,0)(1,1)(2,2); flavor 1 = off-diag (0,1)(0,2)(1,2).
// Waves 0-3 own two col-bands sharing one row-band (A-frags loaded once);
// waves 4-7 own one subtile (CB1 = -1).
static __device__ const int RBt[16]  = {0,1,2,3,4,4,5,5,  0,1,0,1,2,2,3,3};
static __device__ const int CB0t[16] = {0,0,2,2,4,5,4,5,  2,2,4,4,4,5,4,5};
static __device__ const int CB1t[16] = {1,1,3,3,-1,-1,-1,-1,  3,3,5,5,-1,-1,-1,-1};

// Symmetric accessor: only upper-triangular 128-tiles of G are populated.
__device__ __forceinline__ float gsym(const float* __restrict__ G, int i, int j) {
    return ((i >> 7) <= (j >> 7)) ? G[(size_t)i * N_TOTAL + j]
                                  : G[(size_t)j * N_TOTAL + i];
}

// ---------------- fused: read X (fp32) once, cvt in-reg, Gram via MFMA ----------------
__global__ __launch_bounds__(512, 2) void gram_fused_kernel(const float* __restrict__ X,
                                                            float* __restrict__ G) {
    __shared__ char sm[2][N_TOTAL * LROW];   // 2 x 30720 B, bf16 [384][32], 80 B row stride

    // XCD-pair swizzle: both flavors of a strip land on the same XCD (L2 pair-reuse).
    const int B      = blockIdx.x;
    const int x      = B & 7;
    const int i      = B >> 3;
    const int flavor = i & 1;
    const int strip  = x + 8 * (i >> 1);

    const int tid  = threadIdx.x;
    const int wave = tid >> 6;
    const int lane = tid & 63;
    const int r16  = lane & 15;
    const int kg   = lane >> 4;

    const int rb   = RBt[flavor * 8 + wave] * 64;
    const int cb0  = CB0t[flavor * 8 + wave] * 64;
    const int cb1s = CB1t[flavor * 8 + wave];
    const int cb1  = cb1s * 64;

    const size_t cbase = (size_t)strip * COLS_PER;
    const int srow = tid >> 3;        // staging row group base (0..63), +64 per s
    const int scol = (tid & 7) * 4;   // staging col (float4 granularity)

    f32x4 acc0[4][4], acc1[4][4];
#pragma unroll
    for (int m = 0; m < 4; m++)
#pragma unroll
        for (int n = 0; n < 4; n++) { acc0[m][n] = (f32x4)(0.0f); acc1[m][n] = (f32x4)(0.0f); }

    float4 g[6];   // staged fp32 chunk: 6 float4/thread = 384x32 per block

#define LOADG(t)                                                                          \
    _Pragma("unroll") for (int s = 0; s < 6; s++)                                         \
        g[s] = *(const float4*)(X + (size_t)(srow + s * 64) * D_FEAT + cbase +            \
                                (size_t)(t) * CHUNK + scol);

#define WRITEL(buf)                                                                       \
    _Pragma("unroll") for (int s = 0; s < 6; s++) {                                       \
        bf16x4 v;                                                                         \
        v[0] = (__bf16)g[s].x; v[1] = (__bf16)g[s].y;                                     \
        v[2] = (__bf16)g[s].z; v[3] = (__bf16)g[s].w;                                     \
        *(bf16x4*)(&sm[buf][(srow + s * 64) * LROW + scol * 2]) = v;                      \
    }

#define COMPUTE(buf)                                                                      \
    do {                                                                                  \
        const char* bptr = sm[buf];                                                       \
        bf16x8 af[4], bf0[4];                                                             \
        _Pragma("unroll") for (int m = 0; m < 4; m++)                                     \
            af[m] = *(const bf16x8*)(bptr + (rb + m * 16 + r16) * LROW + kg * 16);        \
        _Pragma("unroll") for (int n = 0; n < 4; n++)                                     \
            bf0[n] = *(const bf16x8*)(bptr + (cb0 + n * 16 + r16) * LROW + kg * 16);      \
        _Pragma("unroll") for (int m = 0; m < 4; m++)                                     \
            _Pragma("unroll") for (int n = 0; n < 4; n++)                                 \
                acc0[m][n] = __builtin_amdgcn_mfma_f32_16x16x32_bf16(af[m], bf0[n],       \
                                                                     acc0[m][n], 0, 0, 0);\
        if (cb1s >= 0) {                                                                  \
            bf16x8 bf1[4];                                                                \
            _Pragma("unroll") for (int n = 0; n < 4; n++)                                 \
                bf1[n] = *(const bf16x8*)(bptr + (cb1 + n * 16 + r16) * LROW + kg * 16);  \
            _Pragma("unroll") for (int m = 0; m < 4; m++)                                 \
                _Pragma("unroll") for (int n = 0; n < 4; n++)                             \
                    acc1[m][n] = __builtin_amdgcn_mfma_f32_16x16x32_bf16(af[m], bf1[n],   \
                                                                     acc1[m][n], 0, 0, 0);\
        }                                                                                 \
    } while (0)

    // prologue: chunk 0 staged, chunk 1 in flight
    LOADG(0);
    WRITEL(0);
    LOADG(1);
    __syncthreads();

    for (int t = 0; t < NCH; ++t) {
        const int cur = t & 1;
        COMPUTE(cur);                     // loads for t+1 stay in flight under this
        if (t + 1 < NCH) {
            WRITEL(cur ^ 1);              // waits vmcnt, cvt, stage next buffer
            if (t + 2 < NCH) LOADG(t + 2);
        }
        __syncthreads();
    }
#undef LOADG
#undef WRITEL
#undef COMPUTE

    // C/D layout (verified on gfx950): col = lane&15, row = (lane>>4)*4 + r
    const int crow = (lane >> 4) * 4;
    const int ccol = lane & 15;
#pragma unroll
    for (int m = 0; m < 4; m++)
#pragma unroll
        for (int n = 0; n < 4; n++)
#pragma unroll
            for (int r = 0; r < 4; r++)
                atomicAdd(&G[(size_t)(rb + m * 16 + crow + r) * N_TOTAL + cb0 + n * 16 + ccol],
                          acc0[m][n][r]);
    if (cb1s >= 0) {
#pragma unroll
        for (int m = 0; m < 4; m++)
#pragma unroll
            for (int n = 0; n < 4; n++)
#pragma unroll
                for (int r = 0; r < 4; r++)
                    atomicAdd(&G[(size_t)(rb + m * 16 + crow + r) * N_TOTAL + cb1 + n * 16 + ccol],
                              acc1[m][n][r]);
    }
}

// ---------------- denominators and loss ----------------
__global__ __launch_bounds__(128) void den_kernel(const float* __restrict__ G,
                                                  float* __restrict__ den) {
    const int i = blockIdx.x;
    __shared__ float sInv[N_TOTAL];
    for (int j = threadIdx.x; j < N_TOTAL; j += 128) {
        const float n = sqrtf(G[(size_t)j * N_TOTAL + j]);
        sInv[j] = 1.0f / fmaxf(n, EPS);
    }
    __syncthreads();

    const float mi  = sInv[i] * 10.0f;   // 1/temp = 10
    const int   myc = i & 7;
    float s = 0.0f;
    for (int j = threadIdx.x; j < N_TOTAL; j += 128) {
        if ((j & 7) != myc)
            s += expf(gsym(G, i, j) * mi * sInv[j]);
    }
#pragma unroll
    for (int off = 32; off > 0; off >>= 1) s += __shfl_down(s, off, 64);
    __shared__ float partial[2];
    if ((threadIdx.x & 63) == 0) partial[threadIdx.x >> 6] = s;
    __syncthreads();
    if (threadIdx.x == 0) den[i] = partial[0] + partial[1];
}

__global__ __launch_bounds__(256) void loss_kernel(const float* __restrict__ G,
                                                   const float* __restrict__ den,
                                                   float* __restrict__ out) {
    __shared__ float sInv[N_TOTAL];
    for (int j = threadIdx.x; j < N_TOTAL; j += 256) {
        const float n = sqrtf(G[(size_t)j * N_TOTAL + j]);
        sInv[j] = 1.0f / fmaxf(n, EPS);
    }
    __syncthreads();

    float s = 0.0f;
    for (int idx = threadIdx.x; idx < 7 * BS; idx += 256) {
        const int p   = idx & (BS - 1);
        const int set = idx >> 7;
        int a, b;
        switch (set) {
            case 0:  a = p;                        b = BS + p;                      break;
            case 1:  a = (p + PD) % N_TOTAL;       b = (BS + p + PD) % N_TOTAL;     break;
            case 2:  a = p;                        b = (p + PD) % N_TOTAL;          break;
            case 3:  a = BS + p;                   b = (BS + p + PD) % N_TOTAL;     break;
            case 4:  a = 2 * BS + p;               b = (2 * BS + p + PD) % N_TOTAL; break;
            case 5:  a = BS + p;                   b = 2 * BS + p;                  break;
            default: a = (BS + p + PD) % N_TOTAL;  b = (2 * BS + p + PD) % N_TOTAL; break;
        }
        const float en = expf(gsym(G, a, b) * sInv[a] * sInv[b] * 10.0f);
        s += log1pf(den[a] / en) + log1pf(den[b] / en);
    }
#pragma unroll
    for (int off = 32; off > 0; off >>= 1) s += __shfl_down(s, off, 64);
    __shared__ float partial[4];
    if ((threadIdx.x & 63) == 0) partial[threadIdx.x >> 6] = s;
    __syncthreads();
    if (threadIdx.x == 0)
        out[0] = (partial[0] + partial[1] + partial[2] + partial[3]) / 768.0f;
}

extern "C" void kernel_launch(void* const* d_in, const int* in_sizes, int n_in,
                              void* d_out, int out_size, void* d_ws, size_t ws_size,
                              hipStream_t stream) {
    (void)in_sizes; (void)n_in; (void)out_size; (void)ws_size;
    const float* X   = (const float*)d_in[0];
    float*       out = (float*)d_out;
    float*       G   = (float*)d_ws;                       // 384*384 fp32
    float*       den = G + (size_t)N_TOTAL * N_TOTAL;      // 384 fp32

    hipMemsetAsync(G, 0, (size_t)N_TOTAL * N_TOTAL * sizeof(float), stream);
    gram_fused_kernel<<<NSTRIP * 2, 512, 0, stream>>>(X, G);
    den_kernel<<<N_TOTAL, 128, 0, stream>>>(G, den);
    loss_kernel<<<1, 256, 0, stream>>>(G, den, out);
}